// Round 14
// baseline (239.266 us; speedup 1.0000x reference)
//
#include <hip/hip_runtime.h>
#include <hip/hip_fp16.h>
#include <math.h>

#define N_NODES 50000
#define N_EDGES 800000
#define VOCAB 100
#define DIM 128
#define N_GRAPHS 512
#define LN_EPS 1e-5f
#define NB 196   // ceil(N_NODES/256)
#define SEG 4    // nodes per wave in k_agg2
#define CAP 64   // slot capacity per node (deg~Poisson(16); P(>=64)~e^-125)
#define NWIN 4                                   // dst windows (4 passes)
#define WSZ ((N_NODES + NWIN - 1) / NWIN)        // 12500 nodes per window

using bf16x8  = __attribute__((ext_vector_type(8))) __bf16;
using floatx4 = __attribute__((ext_vector_type(4))) float;

__device__ __forceinline__ unsigned short f2bf(float f) {
    unsigned u = __float_as_uint(f);
    return (unsigned short)((u + 0x7FFF + ((u >> 16) & 1)) >> 16);  // RNE
}

// ---------------- one-pass slot-CSR build (windowed, 4 passes) ----------------
__global__ __launch_bounds__(256) void k_scatter(const int* __restrict__ src,
                                                 const int* __restrict__ dst,
                                                 int* __restrict__ cnt,
                                                 int* __restrict__ slots) {
    int w = blockIdx.x & (NWIN - 1);
    int bg = blockIdx.x >> 2;
    int lo = w * WSZ, hi = lo + WSZ; if (hi > N_NODES) hi = N_NODES;
    int stride = (gridDim.x >> 2) * 256;
    for (int e = bg * 256 + threadIdx.x; e < N_EDGES; e += stride) {
        int d = dst[e];
        if (d >= lo && d < hi) {
            int pos = atomicAdd(&cnt[d], 1);
            slots[d * CAP + pos] = src[e];
        }
    }
}

// ---------------- fused prep: dinv/pw | EW1 = emb@W1 | graph starts ----------------
__global__ __launch_bounds__(256) void k_prep(const int* __restrict__ cnt,
                                              const int* __restrict__ x,
                                              const float* __restrict__ emb,
                                              const float* __restrict__ W1,
                                              const int* __restrict__ batch,
                                              float* __restrict__ dinv,
                                              unsigned* __restrict__ pw,
                                              float* __restrict__ EW1,
                                              int* __restrict__ starts) {
    int b = blockIdx.x, t = threadIdx.x;
    if (b < NB) {                       // range 1: dinv + packed (fp16 dinv | x)
        int i = b * 256 + t;
        if (i < N_NODES) {
            float dv = rsqrtf((float)cnt[i] + 1.0f);
            dinv[i] = dv;
            unsigned hb = (unsigned)__half_as_ushort(__float2half_rn(dv));
            pw[i] = (hb << 16) | (unsigned)x[i];
        }
    } else if (b < NB + 50) {           // range 2: EW1 (100x128 = 50 blocks exactly)
        int idx = (b - NB) * 256 + t;
        int r = idx >> 7, c = idx & 127;
        float acc = 0.f;
        for (int k = 0; k < DIM; k++) acc += emb[r * DIM + k] * W1[k * DIM + c];
        EW1[idx] = acc;
    } else {                            // range 3: starts[g] via binary search
        int g = (b - NB - 50) * 256 + t;
        if (g > N_GRAPHS) return;
        int lo = 0, hi = N_NODES;
        while (lo < hi) { int mid = (lo + hi) >> 1; if (batch[mid] < g) lo = mid + 1; else hi = mid; }
        starts[g] = lo;
    }
}

// ---------------- layer-1 agg + LN + ReLU (bf16 EW1 in LDS, slot-CSR) ----------------
__global__ __launch_bounds__(512) void k_agg1(
    const float* __restrict__ EW1, const unsigned* __restrict__ pw,
    const float* __restrict__ dinv, const int* __restrict__ cnt,
    const int* __restrict__ slots,
    const float* __restrict__ b1, const float* __restrict__ g1,
    const float* __restrict__ be1, unsigned* __restrict__ h1b) {
    __shared__ unsigned ew[VOCAB * 64];  // bf16x2 packed, 25600 B
    for (int idx = threadIdx.x; idx < VOCAB * 64; idx += blockDim.x) {
        float2 v = ((const float2*)EW1)[idx];
        ew[idx] = (unsigned)f2bf(v.x) | ((unsigned)f2bf(v.y) << 16);
    }
    __syncthreads();
    int lane = threadIdx.x & 63;
    int wave = (blockIdx.x * blockDim.x + threadIdx.x) >> 6;
    int nw = (gridDim.x * blockDim.x) >> 6;
    float2 bb = make_float2(b1[2 * lane], b1[2 * lane + 1]);
    float2 gg = make_float2(g1[2 * lane], g1[2 * lane + 1]);
    float2 eb = make_float2(be1[2 * lane], be1[2 * lane + 1]);
    for (int i = wave; i < N_NODES; i += nw) {
        float di = dinv[i];
        int xi = (int)(pw[i] & 0xFFFFu);
        unsigned e0 = ew[xi * 64 + lane];
        float ax = di * __uint_as_float(e0 << 16);
        float ay = di * __uint_as_float(e0 & 0xFFFF0000u);  // self-loop
        int cn = cnt[i];
        unsigned myw = 0;
        if (lane < cn) myw = pw[slots[i * CAP + lane]];
        int j = 0;
        for (; j + 8 <= cn; j += 8) {
            #pragma unroll
            for (int u = 0; u < 8; u++) {
                unsigned w = (unsigned)__shfl((int)myw, j + u, 64);
                int xv = (int)(w & 0xFFFFu);
                float ds = __half2float(__ushort_as_half((unsigned short)(w >> 16)));
                unsigned es = ew[xv * 64 + lane];
                ax += ds * __uint_as_float(es << 16);
                ay += ds * __uint_as_float(es & 0xFFFF0000u);
            }
        }
        for (; j < cn; j++) {
            unsigned w = (unsigned)__shfl((int)myw, j, 64);
            int xv = (int)(w & 0xFFFFu);
            float ds = __half2float(__ushort_as_half((unsigned short)(w >> 16)));
            unsigned es = ew[xv * 64 + lane];
            ax += ds * __uint_as_float(es << 16);
            ay += ds * __uint_as_float(es & 0xFFFF0000u);
        }
        float a0 = di * ax + bb.x, a1 = di * ay + bb.y;
        float s = a0 + a1;
        #pragma unroll
        for (int m = 1; m < 64; m <<= 1) s += __shfl_xor(s, m, 64);
        float mu = s * (1.f / 128.f);
        float d0 = a0 - mu, d1 = a1 - mu;
        float q = d0 * d0 + d1 * d1;
        #pragma unroll
        for (int m = 1; m < 64; m <<= 1) q += __shfl_xor(q, m, 64);
        float r = rsqrtf(q * (1.f / 128.f) + LN_EPS);
        float o0 = fmaxf(d0 * r * gg.x + eb.x, 0.f);
        float o1 = fmaxf(d1 * r * gg.y + eb.y, 0.f);
        h1b[i * 64 + lane] = (unsigned)f2bf(o0) | ((unsigned)f2bf(o1) << 16);
    }
}

// ---------------- v2 = bf16( dinv * (h1 @ W2) ), MFMA 16x16x32 bf16 ----------------
#define W2K 144
__global__ __launch_bounds__(512) void k_mm2(
    const unsigned short* __restrict__ h1b, const float* __restrict__ W2,
    const float* __restrict__ dinv, unsigned short* __restrict__ v2b) {
    __shared__ unsigned short w2t[DIM * W2K];  // 36864 B
    int t = threadIdx.x;
    for (int idx = t * 4; idx < DIM * DIM; idx += 2048) {
        int k = idx >> 7, n = idx & 127;
        float4 v = *(const float4*)&W2[idx];
        w2t[(n + 0) * W2K + k] = f2bf(v.x);
        w2t[(n + 1) * W2K + k] = f2bf(v.y);
        w2t[(n + 2) * W2K + k] = f2bf(v.z);
        w2t[(n + 3) * W2K + k] = f2bf(v.w);
    }
    __syncthreads();
    int lane = t & 63, wv = t >> 6;
    int m = lane & 15, quad = lane >> 4;
    const int NT = N_NODES / 16;  // 3125 row-tiles (exact)
    for (int tile = blockIdx.x * 8 + wv; tile < NT; tile += gridDim.x * 8) {
        const unsigned short* arow = &h1b[(size_t)(tile * 16 + m) * DIM + quad * 8];
        bf16x8 a0 = *(const bf16x8*)(arow);
        bf16x8 a1 = *(const bf16x8*)(arow + 32);
        bf16x8 a2 = *(const bf16x8*)(arow + 64);
        bf16x8 a3 = *(const bf16x8*)(arow + 96);
        int r0 = tile * 16 + quad * 4;
        float dv0 = dinv[r0], dv1 = dinv[r0 + 1], dv2 = dinv[r0 + 2], dv3 = dinv[r0 + 3];
        #pragma unroll
        for (int nt = 0; nt < 8; nt++) {
            const unsigned short* brow = &w2t[(nt * 16 + m) * W2K + quad * 8];
            bf16x8 b0 = *(const bf16x8*)(brow);
            bf16x8 b1 = *(const bf16x8*)(brow + 32);
            bf16x8 b2 = *(const bf16x8*)(brow + 64);
            bf16x8 b3 = *(const bf16x8*)(brow + 96);
            floatx4 c = {0.f, 0.f, 0.f, 0.f};
            c = __builtin_amdgcn_mfma_f32_16x16x32_bf16(a0, b0, c, 0, 0, 0);
            c = __builtin_amdgcn_mfma_f32_16x16x32_bf16(a1, b1, c, 0, 0, 0);
            c = __builtin_amdgcn_mfma_f32_16x16x32_bf16(a2, b2, c, 0, 0, 0);
            c = __builtin_amdgcn_mfma_f32_16x16x32_bf16(a3, b3, c, 0, 0, 0);
            int col = nt * 16 + m;  // C/D: col=lane&15, row=quad*4+reg (m89/m91)
            v2b[(size_t)(r0 + 0) * DIM + col] = f2bf(dv0 * c[0]);
            v2b[(size_t)(r0 + 1) * DIM + col] = f2bf(dv1 * c[1]);
            v2b[(size_t)(r0 + 2) * DIM + col] = f2bf(dv2 * c[2]);
            v2b[(size_t)(r0 + 3) * DIM + col] = f2bf(dv3 * c[3]);
        }
    }
}

// ---------------- layer-2 agg: single-row gathers (REVERT of dual-row regression),
// 16-deep + 8-deep unroll tiers, slot prefetch, pool flush at graph boundary ----------------
__global__ __launch_bounds__(256) void k_agg2(
    const unsigned* __restrict__ v2u, const float* __restrict__ dinv,
    const int* __restrict__ cnt, const int* __restrict__ slots,
    const int* __restrict__ batch,
    const float* __restrict__ b2, const float* __restrict__ g2,
    const float* __restrict__ be2, float* __restrict__ pooled) {
    int lane = threadIdx.x & 63;
    int wave = (blockIdx.x * blockDim.x + threadIdx.x) >> 6;
    int i0 = wave * SEG;
    if (i0 >= N_NODES) return;
    int i1 = i0 + SEG; if (i1 > N_NODES) i1 = N_NODES;
    int nseg = i1 - i0;

    float2 bb = make_float2(b2[2 * lane], b2[2 * lane + 1]);
    float2 gg = make_float2(g2[2 * lane], g2[2 * lane + 1]);
    float2 eb = make_float2(be2[2 * lane], be2[2 * lane + 1]);

    float dv = 0.f; int bv = 0, cv = 0;
    if (lane < nseg) {
        dv = dinv[i0 + lane]; bv = batch[i0 + lane]; cv = cnt[i0 + lane];
    }

    float px = 0.f, py = 0.f;
    int cur_g = __shfl(bv, 0, 64);
    int cn0 = __shfl(cv, 0, 64);
    int mys = (lane < cn0) ? slots[i0 * CAP + lane] : 0;
    for (int k = 0; k < nseg; k++) {
        int i = i0 + k;
        int cn = __shfl(cv, k, 64);
        float di = __shfl(dv, k, 64);
        int g = __shfl(bv, k, 64);
        // prefetch next node's slot row
        int mys_next = 0;
        if (k + 1 < nseg) {
            int cn1 = __shfl(cv, k + 1, 64);
            if (lane < cn1) mys_next = slots[(i + 1) * CAP + lane];
        }
        unsigned u0 = v2u[(size_t)i * 64 + lane];  // self term (dinv_i*hW_i folded)
        float ax = __uint_as_float(u0 << 16);
        float ay = __uint_as_float(u0 & 0xFFFF0000u);
        int j = 0;
        for (; j + 16 <= cn; j += 16) {   // 16 loads in flight (cn~16 avg)
            #pragma unroll
            for (int u = 0; u < 16; u++) {
                int s = __shfl(mys, j + u, 64);
                unsigned uv = v2u[(size_t)s * 64 + lane];
                ax += __uint_as_float(uv << 16);
                ay += __uint_as_float(uv & 0xFFFF0000u);
            }
        }
        for (; j + 8 <= cn; j += 8) {
            #pragma unroll
            for (int u = 0; u < 8; u++) {
                int s = __shfl(mys, j + u, 64);
                unsigned uv = v2u[(size_t)s * 64 + lane];
                ax += __uint_as_float(uv << 16);
                ay += __uint_as_float(uv & 0xFFFF0000u);
            }
        }
        for (; j < cn; j++) {
            int s = __shfl(mys, j, 64);
            unsigned uv = v2u[(size_t)s * 64 + lane];
            ax += __uint_as_float(uv << 16);
            ay += __uint_as_float(uv & 0xFFFF0000u);
        }
        mys = mys_next;
        float a0 = di * ax + bb.x, a1 = di * ay + bb.y;
        float s = a0 + a1;
        #pragma unroll
        for (int m = 1; m < 64; m <<= 1) s += __shfl_xor(s, m, 64);
        float mu = s * (1.f / 128.f);
        float d0 = a0 - mu, d1 = a1 - mu;
        float q = d0 * d0 + d1 * d1;
        #pragma unroll
        for (int m = 1; m < 64; m <<= 1) q += __shfl_xor(q, m, 64);
        float r = rsqrtf(q * (1.f / 128.f) + LN_EPS);
        float o0 = fmaxf(d0 * r * gg.x + eb.x, 0.f);
        float o1 = fmaxf(d1 * r * gg.y + eb.y, 0.f);
        if (g != cur_g) {
            atomicAdd(&pooled[cur_g * DIM + 2 * lane], px);
            atomicAdd(&pooled[cur_g * DIM + 2 * lane + 1], py);
            px = 0.f; py = 0.f; cur_g = g;
        }
        px += o0; py += o1;
    }
    atomicAdd(&pooled[cur_g * DIM + 2 * lane], px);
    atomicAdd(&pooled[cur_g * DIM + 2 * lane + 1], py);
}

// ---------------- out[g] = pooled[g].fcW / max(cnt,1) + fcb ----------------
__global__ void k_out(const float* __restrict__ pooled, const int* __restrict__ starts,
                      const float* __restrict__ fcW, const float* __restrict__ fcb,
                      float* __restrict__ out) {
    int lane = threadIdx.x & 63;
    int g = (blockIdx.x * blockDim.x + threadIdx.x) >> 6;
    if (g >= N_GRAPHS) return;
    float2 p = ((const float2*)pooled)[g * 64 + lane];
    float2 w = ((const float2*)fcW)[lane];
    float s = p.x * w.x + p.y * w.y;
    #pragma unroll
    for (int m = 1; m < 64; m <<= 1) s += __shfl_xor(s, m, 64);
    if (lane == 0) {
        float c = (float)(starts[g + 1] - starts[g]);
        if (c < 1.f) c = 1.f;
        out[g] = s / c + fcb[0];
    }
}

extern "C" void kernel_launch(void* const* d_in, const int* in_sizes, int n_in,
                              void* d_out, int out_size, void* d_ws, size_t ws_size,
                              hipStream_t stream) {
    (void)in_sizes; (void)n_in; (void)out_size; (void)ws_size;
    const int* x    = (const int*)d_in[0];
    const int* src  = (const int*)d_in[1];
    const int* dst  = src + N_EDGES;
    const int* batch = (const int*)d_in[2];
    const float* emb = (const float*)d_in[3];
    const float* W1  = (const float*)d_in[4];
    const float* b1  = (const float*)d_in[5];
    const float* g1  = (const float*)d_in[6];
    const float* be1 = (const float*)d_in[7];
    const float* W2  = (const float*)d_in[8];
    const float* b2  = (const float*)d_in[9];
    const float* g2  = (const float*)d_in[10];
    const float* be2 = (const float*)d_in[11];
    const float* fcW = (const float*)d_in[12];
    const float* fcb = (const float*)d_in[13];
    float* out = (float*)d_out;

    char* wsp = (char*)d_ws;
    size_t off = 0;
    auto alloc = [&](size_t bytes) -> void* {
        void* p = wsp + off;
        off += (bytes + 15) & ~(size_t)15;
        return p;
    };
    // ---- zeroed region ----
    int*   cnt      = (int*)alloc(N_NODES * 4);
    float* pooled   = (float*)alloc(N_GRAPHS * DIM * 4);
    size_t zero_bytes = off;
    // ---- scratch ----
    float*    dinv     = (float*)alloc(N_NODES * 4);
    unsigned* pw       = (unsigned*)alloc(N_NODES * 4);
    int*      slots    = (int*)alloc((size_t)N_NODES * CAP * 4);  // 12.8 MB
    float*    EW1      = (float*)alloc(VOCAB * DIM * 4);
    int*      starts   = (int*)alloc((N_GRAPHS + 1) * 4);
    unsigned short* h1b = (unsigned short*)alloc((size_t)N_NODES * DIM * 2);
    unsigned short* v2b = (unsigned short*)alloc((size_t)N_NODES * DIM * 2);

    hipMemsetAsync(d_ws, 0, zero_bytes, stream);

    k_scatter<<<2048, 256, 0, stream>>>(src, dst, cnt, slots);
    k_prep<<<NB + 50 + 3, 256, 0, stream>>>(cnt, x, emb, W1, batch, dinv, pw, EW1, starts);
    // 1024 blocks x 512 thr, 25.6 KB LDS -> 4 blocks/CU = 32 waves/CU (HW cap)
    k_agg1<<<1024, 512, 0, stream>>>(EW1, pw, dinv, cnt, slots, b1, g1, be1,
                                     (unsigned*)h1b);
    k_mm2<<<391, 512, 0, stream>>>(h1b, W2, dinv, v2b);
    {
        int nwaves = (N_NODES + SEG - 1) / SEG;          // 12500
        int nblocks = (nwaves + 3) / 4;                  // 3125 blocks, 4 waves each
        k_agg2<<<nblocks, 256, 0, stream>>>((const unsigned*)v2b, dinv, cnt, slots,
                                            batch, b2, g2, be2, pooled);
    }
    k_out<<<(N_GRAPHS * 64 + 255) / 256, 256, 0, stream>>>(pooled, starts, fcW, fcb, out);
}

// Round 15
// 226.903 us; speedup vs baseline: 1.0545x; 1.0545x over previous
//
#include <hip/hip_runtime.h>
#include <hip/hip_fp16.h>
#include <math.h>

#define N_NODES 50000
#define N_EDGES 800000
#define VOCAB 100
#define DIM 128
#define N_GRAPHS 512
#define LN_EPS 1e-5f
#define NB 196   // ceil(N_NODES/256)
#define SEG 4    // nodes per wave in k_agg2
#define CAP 64   // slot capacity per node (deg~Poisson(16); P(>=64)~e^-125)
#define NWIN 8                                   // dst windows (== XCDs, proven R11)
#define WSZ ((N_NODES + NWIN - 1) / NWIN)        // 6250 nodes per window

using bf16x8  = __attribute__((ext_vector_type(8))) __bf16;
using floatx4 = __attribute__((ext_vector_type(4))) float;

__device__ __forceinline__ unsigned short f2bf(float f) {
    unsigned u = __float_as_uint(f);
    return (unsigned short)((u + 0x7FFF + ((u >> 16) & 1)) >> 16);  // RNE
}

// ---------------- one-pass slot-CSR build (XCD-windowed, 8 passes) ----------------
__global__ __launch_bounds__(256) void k_scatter(const int* __restrict__ src,
                                                 const int* __restrict__ dst,
                                                 int* __restrict__ cnt,
                                                 int* __restrict__ slots) {
    int w = blockIdx.x & (NWIN - 1);
    int bg = blockIdx.x >> 3;
    int lo = w * WSZ, hi = lo + WSZ; if (hi > N_NODES) hi = N_NODES;
    int stride = (gridDim.x >> 3) * 256;
    for (int e = bg * 256 + threadIdx.x; e < N_EDGES; e += stride) {
        int d = dst[e];
        if (d >= lo && d < hi) {
            int pos = atomicAdd(&cnt[d], 1);
            slots[d * CAP + pos] = src[e];
        }
    }
}

// ---------------- fused prep: dinv/pw | EW1 = emb@W1 | graph starts ----------------
__global__ __launch_bounds__(256) void k_prep(const int* __restrict__ cnt,
                                              const int* __restrict__ x,
                                              const float* __restrict__ emb,
                                              const float* __restrict__ W1,
                                              const int* __restrict__ batch,
                                              float* __restrict__ dinv,
                                              unsigned* __restrict__ pw,
                                              float* __restrict__ EW1,
                                              int* __restrict__ starts) {
    int b = blockIdx.x, t = threadIdx.x;
    if (b < NB) {                       // range 1: dinv + packed (fp16 dinv | x)
        int i = b * 256 + t;
        if (i < N_NODES) {
            float dv = rsqrtf((float)cnt[i] + 1.0f);
            dinv[i] = dv;
            unsigned hb = (unsigned)__half_as_ushort(__float2half_rn(dv));
            pw[i] = (hb << 16) | (unsigned)x[i];
        }
    } else if (b < NB + 50) {           // range 2: EW1 (100x128 = 50 blocks exactly)
        int idx = (b - NB) * 256 + t;
        int r = idx >> 7, c = idx & 127;
        float acc = 0.f;
        for (int k = 0; k < DIM; k++) acc += emb[r * DIM + k] * W1[k * DIM + c];
        EW1[idx] = acc;
    } else {                            // range 3: starts[g] via binary search
        int g = (b - NB - 50) * 256 + t;
        if (g > N_GRAPHS) return;
        int lo = 0, hi = N_NODES;
        while (lo < hi) { int mid = (lo + hi) >> 1; if (batch[mid] < g) lo = mid + 1; else hi = mid; }
        starts[g] = lo;
    }
}

// ---------------- layer-1 agg + LN + ReLU (bf16 EW1 in LDS, slot-CSR) ----------------
// Grid-stride loop software-pipelined: node i+nw's slot->pw gather issued
// before node i's compute (hides the 2-level gather latency).
__global__ __launch_bounds__(512) void k_agg1(
    const float* __restrict__ EW1, const unsigned* __restrict__ pw,
    const float* __restrict__ dinv, const int* __restrict__ cnt,
    const int* __restrict__ slots,
    const float* __restrict__ b1, const float* __restrict__ g1,
    const float* __restrict__ be1, unsigned* __restrict__ h1b) {
    __shared__ unsigned ew[VOCAB * 64];  // bf16x2 packed, 25600 B
    for (int idx = threadIdx.x; idx < VOCAB * 64; idx += blockDim.x) {
        float2 v = ((const float2*)EW1)[idx];
        ew[idx] = (unsigned)f2bf(v.x) | ((unsigned)f2bf(v.y) << 16);
    }
    __syncthreads();
    int lane = threadIdx.x & 63;
    int wave = (blockIdx.x * blockDim.x + threadIdx.x) >> 6;
    int nw = (gridDim.x * blockDim.x) >> 6;
    float2 bb = make_float2(b1[2 * lane], b1[2 * lane + 1]);
    float2 gg = make_float2(g1[2 * lane], g1[2 * lane + 1]);
    float2 eb = make_float2(be1[2 * lane], be1[2 * lane + 1]);
    int i = wave;
    int cn = 0;
    unsigned myw = 0;
    if (i < N_NODES) {
        cn = cnt[i];
        if (lane < cn) myw = pw[slots[i * CAP + lane]];
    }
    while (i < N_NODES) {
        // prefetch next node's edge row (2-level gather) before compute
        int inext = i + nw;
        int cn_next = 0;
        unsigned myw_next = 0;
        if (inext < N_NODES) {
            cn_next = cnt[inext];
            if (lane < cn_next) myw_next = pw[slots[inext * CAP + lane]];
        }
        float di = dinv[i];
        int xi = (int)(pw[i] & 0xFFFFu);
        unsigned e0 = ew[xi * 64 + lane];
        float ax = di * __uint_as_float(e0 << 16);
        float ay = di * __uint_as_float(e0 & 0xFFFF0000u);  // self-loop
        int j = 0;
        for (; j + 8 <= cn; j += 8) {
            #pragma unroll
            for (int u = 0; u < 8; u++) {
                unsigned w = (unsigned)__shfl((int)myw, j + u, 64);
                int xv = (int)(w & 0xFFFFu);
                float ds = __half2float(__ushort_as_half((unsigned short)(w >> 16)));
                unsigned es = ew[xv * 64 + lane];
                ax += ds * __uint_as_float(es << 16);
                ay += ds * __uint_as_float(es & 0xFFFF0000u);
            }
        }
        for (; j < cn; j++) {
            unsigned w = (unsigned)__shfl((int)myw, j, 64);
            int xv = (int)(w & 0xFFFFu);
            float ds = __half2float(__ushort_as_half((unsigned short)(w >> 16)));
            unsigned es = ew[xv * 64 + lane];
            ax += ds * __uint_as_float(es << 16);
            ay += ds * __uint_as_float(es & 0xFFFF0000u);
        }
        float a0 = di * ax + bb.x, a1 = di * ay + bb.y;
        float s = a0 + a1;
        #pragma unroll
        for (int m = 1; m < 64; m <<= 1) s += __shfl_xor(s, m, 64);
        float mu = s * (1.f / 128.f);
        float d0 = a0 - mu, d1 = a1 - mu;
        float q = d0 * d0 + d1 * d1;
        #pragma unroll
        for (int m = 1; m < 64; m <<= 1) q += __shfl_xor(q, m, 64);
        float r = rsqrtf(q * (1.f / 128.f) + LN_EPS);
        float o0 = fmaxf(d0 * r * gg.x + eb.x, 0.f);
        float o1 = fmaxf(d1 * r * gg.y + eb.y, 0.f);
        h1b[(size_t)i * 64 + lane] = (unsigned)f2bf(o0) | ((unsigned)f2bf(o1) << 16);
        i = inext; cn = cn_next; myw = myw_next;
    }
}

// ---------------- v2 = bf16( dinv * (h1 @ W2) ), MFMA 16x16x32 bf16 ----------------
#define W2K 144
__global__ __launch_bounds__(512) void k_mm2(
    const unsigned short* __restrict__ h1b, const float* __restrict__ W2,
    const float* __restrict__ dinv, unsigned short* __restrict__ v2b) {
    __shared__ unsigned short w2t[DIM * W2K];  // 36864 B
    int t = threadIdx.x;
    for (int idx = t * 4; idx < DIM * DIM; idx += 2048) {
        int k = idx >> 7, n = idx & 127;
        float4 v = *(const float4*)&W2[idx];
        w2t[(n + 0) * W2K + k] = f2bf(v.x);
        w2t[(n + 1) * W2K + k] = f2bf(v.y);
        w2t[(n + 2) * W2K + k] = f2bf(v.z);
        w2t[(n + 3) * W2K + k] = f2bf(v.w);
    }
    __syncthreads();
    int lane = t & 63, wv = t >> 6;
    int m = lane & 15, quad = lane >> 4;
    const int NT = N_NODES / 16;  // 3125 row-tiles (exact)
    for (int tile = blockIdx.x * 8 + wv; tile < NT; tile += gridDim.x * 8) {
        const unsigned short* arow = &h1b[(size_t)(tile * 16 + m) * DIM + quad * 8];
        bf16x8 a0 = *(const bf16x8*)(arow);
        bf16x8 a1 = *(const bf16x8*)(arow + 32);
        bf16x8 a2 = *(const bf16x8*)(arow + 64);
        bf16x8 a3 = *(const bf16x8*)(arow + 96);
        int r0 = tile * 16 + quad * 4;
        float dv0 = dinv[r0], dv1 = dinv[r0 + 1], dv2 = dinv[r0 + 2], dv3 = dinv[r0 + 3];
        #pragma unroll
        for (int nt = 0; nt < 8; nt++) {
            const unsigned short* brow = &w2t[(nt * 16 + m) * W2K + quad * 8];
            bf16x8 b0 = *(const bf16x8*)(brow);
            bf16x8 b1 = *(const bf16x8*)(brow + 32);
            bf16x8 b2 = *(const bf16x8*)(brow + 64);
            bf16x8 b3 = *(const bf16x8*)(brow + 96);
            floatx4 c = {0.f, 0.f, 0.f, 0.f};
            c = __builtin_amdgcn_mfma_f32_16x16x32_bf16(a0, b0, c, 0, 0, 0);
            c = __builtin_amdgcn_mfma_f32_16x16x32_bf16(a1, b1, c, 0, 0, 0);
            c = __builtin_amdgcn_mfma_f32_16x16x32_bf16(a2, b2, c, 0, 0, 0);
            c = __builtin_amdgcn_mfma_f32_16x16x32_bf16(a3, b3, c, 0, 0, 0);
            int col = nt * 16 + m;  // C/D: col=lane&15, row=quad*4+reg (m89/m91)
            v2b[(size_t)(r0 + 0) * DIM + col] = f2bf(dv0 * c[0]);
            v2b[(size_t)(r0 + 1) * DIM + col] = f2bf(dv1 * c[1]);
            v2b[(size_t)(r0 + 2) * DIM + col] = f2bf(dv2 * c[2]);
            v2b[(size_t)(r0 + 3) * DIM + col] = f2bf(dv3 * c[3]);
        }
    }
}

// ---------------- layer-2 agg: R11-proven form — single-row gathers, 8-deep
// tier ONLY (16 rows in flight thrashes L2: R13/R14 FETCH 77->111 MB), slot
// prefetch, register pool accumulation with graph-boundary flush ----------------
__global__ __launch_bounds__(256) void k_agg2(
    const unsigned* __restrict__ v2u, const float* __restrict__ dinv,
    const int* __restrict__ cnt, const int* __restrict__ slots,
    const int* __restrict__ batch,
    const float* __restrict__ b2, const float* __restrict__ g2,
    const float* __restrict__ be2, float* __restrict__ pooled) {
    int lane = threadIdx.x & 63;
    int wave = (blockIdx.x * blockDim.x + threadIdx.x) >> 6;
    int i0 = wave * SEG;
    if (i0 >= N_NODES) return;
    int i1 = i0 + SEG; if (i1 > N_NODES) i1 = N_NODES;
    int nseg = i1 - i0;

    float2 bb = make_float2(b2[2 * lane], b2[2 * lane + 1]);
    float2 gg = make_float2(g2[2 * lane], g2[2 * lane + 1]);
    float2 eb = make_float2(be2[2 * lane], be2[2 * lane + 1]);

    float dv = 0.f; int bv = 0, cv = 0;
    if (lane < nseg) {
        dv = dinv[i0 + lane]; bv = batch[i0 + lane]; cv = cnt[i0 + lane];
    }

    float px = 0.f, py = 0.f;
    int cur_g = __shfl(bv, 0, 64);
    int cn0 = __shfl(cv, 0, 64);
    int mys = (lane < cn0) ? slots[i0 * CAP + lane] : 0;
    for (int k = 0; k < nseg; k++) {
        int i = i0 + k;
        int cn = __shfl(cv, k, 64);
        float di = __shfl(dv, k, 64);
        int g = __shfl(bv, k, 64);
        // prefetch next node's slot row
        int mys_next = 0;
        if (k + 1 < nseg) {
            int cn1 = __shfl(cv, k + 1, 64);
            if (lane < cn1) mys_next = slots[(i + 1) * CAP + lane];
        }
        unsigned u0 = v2u[(size_t)i * 64 + lane];  // self term (dinv_i*hW_i folded)
        float ax = __uint_as_float(u0 << 16);
        float ay = __uint_as_float(u0 & 0xFFFF0000u);
        int j = 0;
        for (; j + 8 <= cn; j += 8) {
            #pragma unroll
            for (int u = 0; u < 8; u++) {
                int s = __shfl(mys, j + u, 64);
                unsigned uv = v2u[(size_t)s * 64 + lane];
                ax += __uint_as_float(uv << 16);
                ay += __uint_as_float(uv & 0xFFFF0000u);
            }
        }
        for (; j < cn; j++) {
            int s = __shfl(mys, j, 64);
            unsigned uv = v2u[(size_t)s * 64 + lane];
            ax += __uint_as_float(uv << 16);
            ay += __uint_as_float(uv & 0xFFFF0000u);
        }
        mys = mys_next;
        float a0 = di * ax + bb.x, a1 = di * ay + bb.y;
        float s = a0 + a1;
        #pragma unroll
        for (int m = 1; m < 64; m <<= 1) s += __shfl_xor(s, m, 64);
        float mu = s * (1.f / 128.f);
        float d0 = a0 - mu, d1 = a1 - mu;
        float q = d0 * d0 + d1 * d1;
        #pragma unroll
        for (int m = 1; m < 64; m <<= 1) q += __shfl_xor(q, m, 64);
        float r = rsqrtf(q * (1.f / 128.f) + LN_EPS);
        float o0 = fmaxf(d0 * r * gg.x + eb.x, 0.f);
        float o1 = fmaxf(d1 * r * gg.y + eb.y, 0.f);
        if (g != cur_g) {
            atomicAdd(&pooled[cur_g * DIM + 2 * lane], px);
            atomicAdd(&pooled[cur_g * DIM + 2 * lane + 1], py);
            px = 0.f; py = 0.f; cur_g = g;
        }
        px += o0; py += o1;
    }
    atomicAdd(&pooled[cur_g * DIM + 2 * lane], px);
    atomicAdd(&pooled[cur_g * DIM + 2 * lane + 1], py);
}

// ---------------- out[g] = pooled[g].fcW / max(cnt,1) + fcb ----------------
__global__ void k_out(const float* __restrict__ pooled, const int* __restrict__ starts,
                      const float* __restrict__ fcW, const float* __restrict__ fcb,
                      float* __restrict__ out) {
    int lane = threadIdx.x & 63;
    int g = (blockIdx.x * blockDim.x + threadIdx.x) >> 6;
    if (g >= N_GRAPHS) return;
    float2 p = ((const float2*)pooled)[g * 64 + lane];
    float2 w = ((const float2*)fcW)[lane];
    float s = p.x * w.x + p.y * w.y;
    #pragma unroll
    for (int m = 1; m < 64; m <<= 1) s += __shfl_xor(s, m, 64);
    if (lane == 0) {
        float c = (float)(starts[g + 1] - starts[g]);
        if (c < 1.f) c = 1.f;
        out[g] = s / c + fcb[0];
    }
}

extern "C" void kernel_launch(void* const* d_in, const int* in_sizes, int n_in,
                              void* d_out, int out_size, void* d_ws, size_t ws_size,
                              hipStream_t stream) {
    (void)in_sizes; (void)n_in; (void)out_size; (void)ws_size;
    const int* x    = (const int*)d_in[0];
    const int* src  = (const int*)d_in[1];
    const int* dst  = src + N_EDGES;
    const int* batch = (const int*)d_in[2];
    const float* emb = (const float*)d_in[3];
    const float* W1  = (const float*)d_in[4];
    const float* b1  = (const float*)d_in[5];
    const float* g1  = (const float*)d_in[6];
    const float* be1 = (const float*)d_in[7];
    const float* W2  = (const float*)d_in[8];
    const float* b2  = (const float*)d_in[9];
    const float* g2  = (const float*)d_in[10];
    const float* be2 = (const float*)d_in[11];
    const float* fcW = (const float*)d_in[12];
    const float* fcb = (const float*)d_in[13];
    float* out = (float*)d_out;

    char* wsp = (char*)d_ws;
    size_t off = 0;
    auto alloc = [&](size_t bytes) -> void* {
        void* p = wsp + off;
        off += (bytes + 15) & ~(size_t)15;
        return p;
    };
    // ---- zeroed region ----
    int*   cnt      = (int*)alloc(N_NODES * 4);
    float* pooled   = (float*)alloc(N_GRAPHS * DIM * 4);
    size_t zero_bytes = off;
    // ---- scratch ----
    float*    dinv     = (float*)alloc(N_NODES * 4);
    unsigned* pw       = (unsigned*)alloc(N_NODES * 4);
    int*      slots    = (int*)alloc((size_t)N_NODES * CAP * 4);  // 12.8 MB
    float*    EW1      = (float*)alloc(VOCAB * DIM * 4);
    int*      starts   = (int*)alloc((N_GRAPHS + 1) * 4);
    unsigned short* h1b = (unsigned short*)alloc((size_t)N_NODES * DIM * 2);
    unsigned short* v2b = (unsigned short*)alloc((size_t)N_NODES * DIM * 2);

    hipMemsetAsync(d_ws, 0, zero_bytes, stream);

    k_scatter<<<2048, 256, 0, stream>>>(src, dst, cnt, slots);
    k_prep<<<NB + 50 + 3, 256, 0, stream>>>(cnt, x, emb, W1, batch, dinv, pw, EW1, starts);
    // 1024 blocks x 512 thr, 25.6 KB LDS -> 4 blocks/CU = 32 waves/CU (HW cap)
    k_agg1<<<1024, 512, 0, stream>>>(EW1, pw, dinv, cnt, slots, b1, g1, be1,
                                     (unsigned*)h1b);
    k_mm2<<<391, 512, 0, stream>>>(h1b, W2, dinv, v2b);
    {
        int nwaves = (N_NODES + SEG - 1) / SEG;          // 12500
        int nblocks = (nwaves + 3) / 4;                  // 3125 blocks, 4 waves each
        k_agg2<<<nblocks, 256, 0, stream>>>((const unsigned*)v2b, dinv, cnt, slots,
                                            batch, b2, g2, be2, pooled);
    }
    k_out<<<(N_GRAPHS * 64 + 255) / 256, 256, 0, stream>>>(pooled, starts, fcW, fcb, out);
}

// Round 16
// 225.417 us; speedup vs baseline: 1.0614x; 1.0066x over previous
//
#include <hip/hip_runtime.h>
#include <hip/hip_fp16.h>
#include <math.h>

#define N_NODES 50000
#define N_EDGES 800000
#define VOCAB 100
#define DIM 128
#define N_GRAPHS 512
#define LN_EPS 1e-5f
#define NB 196   // ceil(N_NODES/256)
#define SEG 4    // nodes per wave in k_agg2
#define CAP 64   // slot capacity per node (deg~Poisson(16); P(>=64)~e^-125)
#define NWIN 8                                   // dst windows (== XCDs, proven R11)
#define WSZ ((N_NODES + NWIN - 1) / NWIN)        // 6250 nodes per window
#define SCAT_BLKS 2048                           // edge-pass blocks in k_scatter

using bf16x8  = __attribute__((ext_vector_type(8))) __bf16;
using floatx4 = __attribute__((ext_vector_type(4))) float;

__device__ __forceinline__ unsigned short f2bf(float f) {
    unsigned u = __float_as_uint(f);
    return (unsigned short)((u + 0x7FFF + ((u >> 16) & 1)) >> 16);  // RNE
}

// ---------------- slot-CSR build (XCD-windowed) + off-chain prep in tail blocks:
// blocks [0,2048): windowed edge passes; [2048,2098): EW1 = emb@W1;
// [2098,2101): graph starts. EW1/starts have no dependency on the edge data,
// so they hide under the scatter instead of serializing after it. ----------------
__global__ __launch_bounds__(256) void k_scatter(const int* __restrict__ src,
                                                 const int* __restrict__ dst,
                                                 int* __restrict__ cnt,
                                                 int* __restrict__ slots,
                                                 const float* __restrict__ emb,
                                                 const float* __restrict__ W1,
                                                 const int* __restrict__ batch,
                                                 float* __restrict__ EW1,
                                                 int* __restrict__ starts) {
    int b = blockIdx.x, t = threadIdx.x;
    if (b < SCAT_BLKS) {
        int w = b & (NWIN - 1);
        int bg = b >> 3;
        int lo = w * WSZ, hi = lo + WSZ; if (hi > N_NODES) hi = N_NODES;
        const int stride = (SCAT_BLKS >> 3) * 256;
        for (int e = bg * 256 + t; e < N_EDGES; e += stride) {
            int d = dst[e];
            if (d >= lo && d < hi) {
                int pos = atomicAdd(&cnt[d], 1);
                slots[d * CAP + pos] = src[e];
            }
        }
    } else if (b < SCAT_BLKS + 50) {    // EW1 (100x128 = 50 blocks exactly)
        int idx = (b - SCAT_BLKS) * 256 + t;
        int r = idx >> 7, c = idx & 127;
        float acc = 0.f;
        for (int k = 0; k < DIM; k++) acc += emb[r * DIM + k] * W1[k * DIM + c];
        EW1[idx] = acc;
    } else {                            // starts[g] via binary search
        int g = (b - SCAT_BLKS - 50) * 256 + t;
        if (g > N_GRAPHS) return;
        int lo = 0, hi = N_NODES;
        while (lo < hi) { int mid = (lo + hi) >> 1; if (batch[mid] < g) lo = mid + 1; else hi = mid; }
        starts[g] = lo;
    }
}

// ---------------- prep: dinv/pw from cnt | zero pooled ----------------
__global__ __launch_bounds__(256) void k_prep(const int* __restrict__ cnt,
                                              const int* __restrict__ x,
                                              float* __restrict__ dinv,
                                              unsigned* __restrict__ pw,
                                              float* __restrict__ pooled) {
    int b = blockIdx.x, t = threadIdx.x;
    if (b < NB) {                       // dinv + packed (fp16 dinv | x)
        int i = b * 256 + t;
        if (i < N_NODES) {
            float dv = rsqrtf((float)cnt[i] + 1.0f);
            dinv[i] = dv;
            unsigned hb = (unsigned)__half_as_ushort(__float2half_rn(dv));
            pw[i] = (hb << 16) | (unsigned)x[i];
        }
    } else {                            // zero pooled: 64 blocks x 256 thr x float4
        int idx = (b - NB) * 256 + t;
        *(float4*)&pooled[idx * 4] = make_float4(0.f, 0.f, 0.f, 0.f);
    }
}

// ---------------- layer-1 agg + LN + ReLU (bf16 EW1 in LDS, slot-CSR) ----------------
// Grid-stride loop software-pipelined: node i+nw's slot->pw gather issued
// before node i's compute (hides the 2-level gather latency).
__global__ __launch_bounds__(512) void k_agg1(
    const float* __restrict__ EW1, const unsigned* __restrict__ pw,
    const float* __restrict__ dinv, const int* __restrict__ cnt,
    const int* __restrict__ slots,
    const float* __restrict__ b1, const float* __restrict__ g1,
    const float* __restrict__ be1, unsigned* __restrict__ h1b) {
    __shared__ unsigned ew[VOCAB * 64];  // bf16x2 packed, 25600 B
    for (int idx = threadIdx.x; idx < VOCAB * 64; idx += blockDim.x) {
        float2 v = ((const float2*)EW1)[idx];
        ew[idx] = (unsigned)f2bf(v.x) | ((unsigned)f2bf(v.y) << 16);
    }
    __syncthreads();
    int lane = threadIdx.x & 63;
    int wave = (blockIdx.x * blockDim.x + threadIdx.x) >> 6;
    int nw = (gridDim.x * blockDim.x) >> 6;
    float2 bb = make_float2(b1[2 * lane], b1[2 * lane + 1]);
    float2 gg = make_float2(g1[2 * lane], g1[2 * lane + 1]);
    float2 eb = make_float2(be1[2 * lane], be1[2 * lane + 1]);
    int i = wave;
    int cn = 0;
    unsigned myw = 0;
    if (i < N_NODES) {
        cn = cnt[i];
        if (lane < cn) myw = pw[slots[i * CAP + lane]];
    }
    while (i < N_NODES) {
        int inext = i + nw;
        int cn_next = 0;
        unsigned myw_next = 0;
        if (inext < N_NODES) {
            cn_next = cnt[inext];
            if (lane < cn_next) myw_next = pw[slots[inext * CAP + lane]];
        }
        float di = dinv[i];
        int xi = (int)(pw[i] & 0xFFFFu);
        unsigned e0 = ew[xi * 64 + lane];
        float ax = di * __uint_as_float(e0 << 16);
        float ay = di * __uint_as_float(e0 & 0xFFFF0000u);  // self-loop
        int j = 0;
        for (; j + 8 <= cn; j += 8) {
            #pragma unroll
            for (int u = 0; u < 8; u++) {
                unsigned w = (unsigned)__shfl((int)myw, j + u, 64);
                int xv = (int)(w & 0xFFFFu);
                float ds = __half2float(__ushort_as_half((unsigned short)(w >> 16)));
                unsigned es = ew[xv * 64 + lane];
                ax += ds * __uint_as_float(es << 16);
                ay += ds * __uint_as_float(es & 0xFFFF0000u);
            }
        }
        for (; j < cn; j++) {
            unsigned w = (unsigned)__shfl((int)myw, j, 64);
            int xv = (int)(w & 0xFFFFu);
            float ds = __half2float(__ushort_as_half((unsigned short)(w >> 16)));
            unsigned es = ew[xv * 64 + lane];
            ax += ds * __uint_as_float(es << 16);
            ay += ds * __uint_as_float(es & 0xFFFF0000u);
        }
        float a0 = di * ax + bb.x, a1 = di * ay + bb.y;
        float s = a0 + a1;
        #pragma unroll
        for (int m = 1; m < 64; m <<= 1) s += __shfl_xor(s, m, 64);
        float mu = s * (1.f / 128.f);
        float d0 = a0 - mu, d1 = a1 - mu;
        float q = d0 * d0 + d1 * d1;
        #pragma unroll
        for (int m = 1; m < 64; m <<= 1) q += __shfl_xor(q, m, 64);
        float r = rsqrtf(q * (1.f / 128.f) + LN_EPS);
        float o0 = fmaxf(d0 * r * gg.x + eb.x, 0.f);
        float o1 = fmaxf(d1 * r * gg.y + eb.y, 0.f);
        h1b[(size_t)i * 64 + lane] = (unsigned)f2bf(o0) | ((unsigned)f2bf(o1) << 16);
        i = inext; cn = cn_next; myw = myw_next;
    }
}

// ---------------- v2 = bf16( dinv * (h1 @ W2) ), MFMA 16x16x32 bf16 ----------------
#define W2K 144
__global__ __launch_bounds__(512) void k_mm2(
    const unsigned short* __restrict__ h1b, const float* __restrict__ W2,
    const float* __restrict__ dinv, unsigned short* __restrict__ v2b) {
    __shared__ unsigned short w2t[DIM * W2K];  // 36864 B
    int t = threadIdx.x;
    for (int idx = t * 4; idx < DIM * DIM; idx += 2048) {
        int k = idx >> 7, n = idx & 127;
        float4 v = *(const float4*)&W2[idx];
        w2t[(n + 0) * W2K + k] = f2bf(v.x);
        w2t[(n + 1) * W2K + k] = f2bf(v.y);
        w2t[(n + 2) * W2K + k] = f2bf(v.z);
        w2t[(n + 3) * W2K + k] = f2bf(v.w);
    }
    __syncthreads();
    int lane = t & 63, wv = t >> 6;
    int m = lane & 15, quad = lane >> 4;
    const int NT = N_NODES / 16;  // 3125 row-tiles (exact)
    for (int tile = blockIdx.x * 8 + wv; tile < NT; tile += gridDim.x * 8) {
        const unsigned short* arow = &h1b[(size_t)(tile * 16 + m) * DIM + quad * 8];
        bf16x8 a0 = *(const bf16x8*)(arow);
        bf16x8 a1 = *(const bf16x8*)(arow + 32);
        bf16x8 a2 = *(const bf16x8*)(arow + 64);
        bf16x8 a3 = *(const bf16x8*)(arow + 96);
        int r0 = tile * 16 + quad * 4;
        float dv0 = dinv[r0], dv1 = dinv[r0 + 1], dv2 = dinv[r0 + 2], dv3 = dinv[r0 + 3];
        #pragma unroll
        for (int nt = 0; nt < 8; nt++) {
            const unsigned short* brow = &w2t[(nt * 16 + m) * W2K + quad * 8];
            bf16x8 b0 = *(const bf16x8*)(brow);
            bf16x8 b1 = *(const bf16x8*)(brow + 32);
            bf16x8 b2 = *(const bf16x8*)(brow + 64);
            bf16x8 b3 = *(const bf16x8*)(brow + 96);
            floatx4 c = {0.f, 0.f, 0.f, 0.f};
            c = __builtin_amdgcn_mfma_f32_16x16x32_bf16(a0, b0, c, 0, 0, 0);
            c = __builtin_amdgcn_mfma_f32_16x16x32_bf16(a1, b1, c, 0, 0, 0);
            c = __builtin_amdgcn_mfma_f32_16x16x32_bf16(a2, b2, c, 0, 0, 0);
            c = __builtin_amdgcn_mfma_f32_16x16x32_bf16(a3, b3, c, 0, 0, 0);
            int col = nt * 16 + m;  // C/D: col=lane&15, row=quad*4+reg (m89/m91)
            v2b[(size_t)(r0 + 0) * DIM + col] = f2bf(dv0 * c[0]);
            v2b[(size_t)(r0 + 1) * DIM + col] = f2bf(dv1 * c[1]);
            v2b[(size_t)(r0 + 2) * DIM + col] = f2bf(dv2 * c[2]);
            v2b[(size_t)(r0 + 3) * DIM + col] = f2bf(dv3 * c[3]);
        }
    }
}

// ---------------- layer-2 agg: R11-proven form — single-row gathers, 8-deep
// tier ONLY (16 rows in flight thrashes L2: R13/R14 FETCH 77->111 MB), slot
// prefetch, register pool accumulation with graph-boundary flush ----------------
__global__ __launch_bounds__(256) void k_agg2(
    const unsigned* __restrict__ v2u, const float* __restrict__ dinv,
    const int* __restrict__ cnt, const int* __restrict__ slots,
    const int* __restrict__ batch,
    const float* __restrict__ b2, const float* __restrict__ g2,
    const float* __restrict__ be2, float* __restrict__ pooled) {
    int lane = threadIdx.x & 63;
    int wave = (blockIdx.x * blockDim.x + threadIdx.x) >> 6;
    int i0 = wave * SEG;
    if (i0 >= N_NODES) return;
    int i1 = i0 + SEG; if (i1 > N_NODES) i1 = N_NODES;
    int nseg = i1 - i0;

    float2 bb = make_float2(b2[2 * lane], b2[2 * lane + 1]);
    float2 gg = make_float2(g2[2 * lane], g2[2 * lane + 1]);
    float2 eb = make_float2(be2[2 * lane], be2[2 * lane + 1]);

    float dv = 0.f; int bv = 0, cv = 0;
    if (lane < nseg) {
        dv = dinv[i0 + lane]; bv = batch[i0 + lane]; cv = cnt[i0 + lane];
    }

    float px = 0.f, py = 0.f;
    int cur_g = __shfl(bv, 0, 64);
    int cn0 = __shfl(cv, 0, 64);
    int mys = (lane < cn0) ? slots[i0 * CAP + lane] : 0;
    for (int k = 0; k < nseg; k++) {
        int i = i0 + k;
        int cn = __shfl(cv, k, 64);
        float di = __shfl(dv, k, 64);
        int g = __shfl(bv, k, 64);
        // prefetch next node's slot row
        int mys_next = 0;
        if (k + 1 < nseg) {
            int cn1 = __shfl(cv, k + 1, 64);
            if (lane < cn1) mys_next = slots[(i + 1) * CAP + lane];
        }
        unsigned u0 = v2u[(size_t)i * 64 + lane];  // self term (dinv_i*hW_i folded)
        float ax = __uint_as_float(u0 << 16);
        float ay = __uint_as_float(u0 & 0xFFFF0000u);
        int j = 0;
        for (; j + 8 <= cn; j += 8) {
            #pragma unroll
            for (int u = 0; u < 8; u++) {
                int s = __shfl(mys, j + u, 64);
                unsigned uv = v2u[(size_t)s * 64 + lane];
                ax += __uint_as_float(uv << 16);
                ay += __uint_as_float(uv & 0xFFFF0000u);
            }
        }
        for (; j < cn; j++) {
            int s = __shfl(mys, j, 64);
            unsigned uv = v2u[(size_t)s * 64 + lane];
            ax += __uint_as_float(uv << 16);
            ay += __uint_as_float(uv & 0xFFFF0000u);
        }
        mys = mys_next;
        float a0 = di * ax + bb.x, a1 = di * ay + bb.y;
        float s = a0 + a1;
        #pragma unroll
        for (int m = 1; m < 64; m <<= 1) s += __shfl_xor(s, m, 64);
        float mu = s * (1.f / 128.f);
        float d0 = a0 - mu, d1 = a1 - mu;
        float q = d0 * d0 + d1 * d1;
        #pragma unroll
        for (int m = 1; m < 64; m <<= 1) q += __shfl_xor(q, m, 64);
        float r = rsqrtf(q * (1.f / 128.f) + LN_EPS);
        float o0 = fmaxf(d0 * r * gg.x + eb.x, 0.f);
        float o1 = fmaxf(d1 * r * gg.y + eb.y, 0.f);
        if (g != cur_g) {
            atomicAdd(&pooled[cur_g * DIM + 2 * lane], px);
            atomicAdd(&pooled[cur_g * DIM + 2 * lane + 1], py);
            px = 0.f; py = 0.f; cur_g = g;
        }
        px += o0; py += o1;
    }
    atomicAdd(&pooled[cur_g * DIM + 2 * lane], px);
    atomicAdd(&pooled[cur_g * DIM + 2 * lane + 1], py);
}

// ---------------- out[g] = pooled[g].fcW / max(cnt,1) + fcb ----------------
__global__ void k_out(const float* __restrict__ pooled, const int* __restrict__ starts,
                      const float* __restrict__ fcW, const float* __restrict__ fcb,
                      float* __restrict__ out) {
    int lane = threadIdx.x & 63;
    int g = (blockIdx.x * blockDim.x + threadIdx.x) >> 6;
    if (g >= N_GRAPHS) return;
    float2 p = ((const float2*)pooled)[g * 64 + lane];
    float2 w = ((const float2*)fcW)[lane];
    float s = p.x * w.x + p.y * w.y;
    #pragma unroll
    for (int m = 1; m < 64; m <<= 1) s += __shfl_xor(s, m, 64);
    if (lane == 0) {
        float c = (float)(starts[g + 1] - starts[g]);
        if (c < 1.f) c = 1.f;
        out[g] = s / c + fcb[0];
    }
}

extern "C" void kernel_launch(void* const* d_in, const int* in_sizes, int n_in,
                              void* d_out, int out_size, void* d_ws, size_t ws_size,
                              hipStream_t stream) {
    (void)in_sizes; (void)n_in; (void)out_size; (void)ws_size;
    const int* x    = (const int*)d_in[0];
    const int* src  = (const int*)d_in[1];
    const int* dst  = src + N_EDGES;
    const int* batch = (const int*)d_in[2];
    const float* emb = (const float*)d_in[3];
    const float* W1  = (const float*)d_in[4];
    const float* b1  = (const float*)d_in[5];
    const float* g1  = (const float*)d_in[6];
    const float* be1 = (const float*)d_in[7];
    const float* W2  = (const float*)d_in[8];
    const float* b2  = (const float*)d_in[9];
    const float* g2  = (const float*)d_in[10];
    const float* be2 = (const float*)d_in[11];
    const float* fcW = (const float*)d_in[12];
    const float* fcb = (const float*)d_in[13];
    float* out = (float*)d_out;

    char* wsp = (char*)d_ws;
    size_t off = 0;
    auto alloc = [&](size_t bytes) -> void* {
        void* p = wsp + off;
        off += (bytes + 15) & ~(size_t)15;
        return p;
    };
    // ---- zeroed region (cnt only; pooled zeroed in k_prep) ----
    int*   cnt      = (int*)alloc(N_NODES * 4);
    size_t zero_bytes = off;
    // ---- scratch ----
    float*    pooled   = (float*)alloc(N_GRAPHS * DIM * 4);
    float*    dinv     = (float*)alloc(N_NODES * 4);
    unsigned* pw       = (unsigned*)alloc(N_NODES * 4);
    int*      slots    = (int*)alloc((size_t)N_NODES * CAP * 4);  // 12.8 MB
    float*    EW1      = (float*)alloc(VOCAB * DIM * 4);
    int*      starts   = (int*)alloc((N_GRAPHS + 1) * 4);
    unsigned short* h1b = (unsigned short*)alloc((size_t)N_NODES * DIM * 2);
    unsigned short* v2b = (unsigned short*)alloc((size_t)N_NODES * DIM * 2);

    hipMemsetAsync(d_ws, 0, zero_bytes, stream);

    // edge passes + (EW1 | starts) in tail blocks, concurrent with scatter
    k_scatter<<<SCAT_BLKS + 53, 256, 0, stream>>>(src, dst, cnt, slots,
                                                  emb, W1, batch, EW1, starts);
    // dinv/pw from cnt + zero pooled (64 blocks x 1024 floats)
    k_prep<<<NB + 64, 256, 0, stream>>>(cnt, x, dinv, pw, pooled);
    // 1024 blocks x 512 thr, 25.6 KB LDS -> 4 blocks/CU = 32 waves/CU (HW cap)
    k_agg1<<<1024, 512, 0, stream>>>(EW1, pw, dinv, cnt, slots, b1, g1, be1,
                                     (unsigned*)h1b);
    k_mm2<<<391, 512, 0, stream>>>(h1b, W2, dinv, v2b);
    {
        int nwaves = (N_NODES + SEG - 1) / SEG;          // 12500
        int nblocks = (nwaves + 3) / 4;                  // 3125 blocks, 4 waves each
        k_agg2<<<nblocks, 256, 0, stream>>>((const unsigned*)v2b, dinv, cnt, slots,
                                            batch, b2, g2, be2, pooled);
    }
    k_out<<<(N_GRAPHS * 64 + 255) / 256, 256, 0, stream>>>(pooled, starts, fcW, fcb, out);
}